// Round 1
// 439.221 us; speedup vs baseline: 1.2550x; 1.2550x over previous
//
#include <hip/hip_runtime.h>
#include <hip/hip_bf16.h>

#define S_LEN 2048
#define HID   2048
#define NH    32
#define NKV   8
#define HD    64
#define ROT   16
#define QKV_N 3072
#define ROWS  4096   // B*S

typedef __attribute__((ext_vector_type(8))) short short8;
typedef __attribute__((ext_vector_type(8))) unsigned short ushort8;
typedef __attribute__((ext_vector_type(4))) float floatx4;

static __device__ __forceinline__ float bf2f(ushort u) {
  union { unsigned int i; float f; } v; v.i = ((unsigned int)u) << 16; return v.f;
}
static __device__ __forceinline__ ushort f2bf(float f) {
  union { __hip_bfloat16 h; ushort u; } v; v.h = __float2bfloat16(f); return v.u;
}

// ---------------------------------------------------------------------------
// fp32 -> bf16 convert, 8 elems/thread (inputs are fp32)
// ---------------------------------------------------------------------------
__global__ __launch_bounds__(256)
void cvt_f32_bf16(const float* __restrict__ in, ushort* __restrict__ out, int n8) {
  const int i = blockIdx.x * 256 + threadIdx.x;
  if (i >= n8) return;
  const float4 a = ((const float4*)in)[2 * i];
  const float4 b = ((const float4*)in)[2 * i + 1];
  ushort8 o;
  o[0] = f2bf(a.x); o[1] = f2bf(a.y); o[2] = f2bf(a.z); o[3] = f2bf(a.w);
  o[4] = f2bf(b.x); o[5] = f2bf(b.y); o[6] = f2bf(b.z); o[7] = f2bf(b.w);
  ((ushort8*)out)[i] = o;
}

// ---------------------------------------------------------------------------
// NT GEMM (m97 structure): 128x128 tile, BK=32, global_load_lds width-16,
// 4 waves x 4x4 mfma_f32_16x16x32_bf16. OUT_BF16 ? bf16 C : fp32 C.
// ---------------------------------------------------------------------------
template<bool OUT_BF16>
__global__ __launch_bounds__(256, 2)
void gemm_nt(const ushort* __restrict__ A, const ushort* __restrict__ B,
             void* __restrict__ Cout, int M, int N, int K) {
  __shared__ ushort lA[128 * 32];
  __shared__ ushort lB[128 * 32];
  const int tid  = threadIdx.x;
  const int wave = tid >> 6, lane = tid & 63;
  const int wr = (wave >> 1) * 64, wc = (wave & 1) * 64;
  const int frow = lane & 15, quad = lane >> 4;
  const int fk = quad * 8;
  const int srow = lane >> 2, skk = (lane & 3) * 8;
  const size_t bm = (size_t)blockIdx.y * 128;
  const size_t bn = (size_t)blockIdx.x * 128;
  const ushort* Ab = A + bm * K;
  const ushort* Bb = B + bn * K;
  floatx4 acc[4][4] = {};

  for (int k0 = 0; k0 < K; k0 += 32) {
    __syncthreads();
    {
      const int c0 = wave * 2;
      const ushort* ga = Ab + (size_t)(c0 * 16 + srow) * K + (k0 + skk);
      const ushort* gb = Bb + (size_t)(c0 * 16 + srow) * K + (k0 + skk);
      __builtin_amdgcn_global_load_lds((const __attribute__((address_space(1))) void*)ga,
          (__attribute__((address_space(3))) void*)&lA[c0 * 512], 16, 0, 0);
      __builtin_amdgcn_global_load_lds((const __attribute__((address_space(1))) void*)gb,
          (__attribute__((address_space(3))) void*)&lB[c0 * 512], 16, 0, 0);
      __builtin_amdgcn_global_load_lds((const __attribute__((address_space(1))) void*)(ga + (size_t)16 * K),
          (__attribute__((address_space(3))) void*)&lA[(c0 + 1) * 512], 16, 0, 0);
      __builtin_amdgcn_global_load_lds((const __attribute__((address_space(1))) void*)(gb + (size_t)16 * K),
          (__attribute__((address_space(3))) void*)&lB[(c0 + 1) * 512], 16, 0, 0);
    }
    __syncthreads();

    short8 af[4], bfr[4];
#pragma unroll
    for (int i = 0; i < 4; ++i)
      af[i] = *(const short8*)&lA[(wr + i * 16 + frow) * 32 + fk];
#pragma unroll
    for (int i = 0; i < 4; ++i)
      bfr[i] = *(const short8*)&lB[(wc + i * 16 + frow) * 32 + fk];
#pragma unroll
    for (int i = 0; i < 4; ++i)
#pragma unroll
      for (int j = 0; j < 4; ++j)
        acc[i][j] = __builtin_amdgcn_mfma_f32_16x16x32_bf16(af[i], bfr[j], acc[i][j], 0, 0, 0);
  }

  const int r0 = quad * 4;
#pragma unroll
  for (int i = 0; i < 4; ++i) {
#pragma unroll
    for (int r = 0; r < 4; ++r) {
      const size_t row = bm + wr + i * 16 + r0 + r;
#pragma unroll
      for (int j = 0; j < 4; ++j) {
        const size_t col = bn + wc + j * 16 + frow;
        if (OUT_BF16) ((ushort*)Cout)[row * N + col] = f2bf(acc[i][j][r]);
        else          ((float*)Cout)[row * N + col] = acc[i][j][r];
      }
    }
  }
}

// ---------------------------------------------------------------------------
// Per-head LayerNorm + partial NeoX RoPE + split. One wave per (row, slot).
// slot 0..31 = q, 32..39 = k, 40..47 = v. LN weights fp32.
// Q -> (b,h,s,d); K -> (b,kv,s,d); V -> (b,kv,d,s) transposed for flash.
// ---------------------------------------------------------------------------
__global__ __launch_bounds__(256)
void ln_rope_split(const ushort* __restrict__ qkv, const int* __restrict__ pos_ids,
                   const float* __restrict__ qw, const float* __restrict__ kw,
                   ushort* __restrict__ Q, ushort* __restrict__ Kk, ushort* __restrict__ Vt) {
  const int gw   = (blockIdx.x * 256 + threadIdx.x) >> 6;
  const int lane = threadIdx.x & 63;
  const int row  = gw / 48;
  const int slot = gw - row * 48;
  const int b = row >> 11, s = row & 2047;
  const float x = bf2f(qkv[(size_t)row * QKV_N + slot * 64 + lane]);

  if (slot < 40) {
    float s1 = x, s2 = x * x;
#pragma unroll
    for (int d = 1; d < 64; d <<= 1) { s1 += __shfl_xor(s1, d); s2 += __shfl_xor(s2, d); }
    const float mu  = s1 * (1.0f / 64.0f);
    const float var = s2 * (1.0f / 64.0f) - mu * mu;
    const float w = (slot < 32) ? qw[slot * 64 + lane] : kw[(slot - 32) * 64 + lane];
    float y = (x - mu) * rsqrtf(var + 1e-5f) * w;
    if (lane < ROT) {
      const int dd = lane & 7;
      const float invf = powf(10000.0f, -(float)dd * 0.125f);
      const float fr = (float)pos_ids[row] * invf;
      const float c = cosf(fr), sn = sinf(fr);
      const float yp = __shfl_xor(y, 8);
      y = (lane < 8) ? (y * c - yp * sn) : (y * c + yp * sn);
    }
    if (slot < 32)
      Q[(((size_t)b * NH + slot) * S_LEN + s) * HD + lane] = f2bf(y);
    else
      Kk[(((size_t)b * NKV + (slot - 32)) * S_LEN + s) * HD + lane] = f2bf(y);
  } else {
    const int kvh = slot - 40;
    Vt[(((size_t)b * NKV + kvh) * HD + lane) * S_LEN + s] = f2bf(x);
  }
}

// ---------------------------------------------------------------------------
// Causal GQA flash attention, FIXED-CAP softmax (no online rescaling):
// LayerNorm bounds |q|,|k| <= 8 -> s = q.k/8 in [-8.1,8.1]; p = exp(s - 9)
// cannot overflow; softmax shift-invariance makes it exact.
//
// v2 structure (latency-bound fix — MfmaUtil was 5%, all pipes idle):
//  * QBLK=32: two 16-row Q fragments per wave share each K/V load and each
//    LDS P-bounce -> 2x MFMA per chain, half the waves (4096).
//  * K register double-buffer: next K tile issued BEFORE the exp/LDS/PV
//    section -> global latency hides under ~300cyc of compute. V issued at
//    body start, consumed at body end (issue-early/use-late).
//  * XCD-bijective block remap: vid=(bb&7)*128+(bb>>3) gives each XCD 8
//    consecutive heads -> KV working set ~1.3MB/XCD, L2-resident.
//    Per-block qt set {g,31-g,32+g,63-g} equalizes block work; rotation
//    (vid>>5)&3 mixes heavy/light waves across SIMDs.
//  * P-buffer XOR swizzle (row stride 128B, slot^=row&7): ds_read_b128 goes
//    8-way -> 2-way (free), writes 4-way -> 2-way.
// ---------------------------------------------------------------------------
#define SMAX 9.0f

#define FA_BODY(KC0,KC1,KC2,KC3, KN0,KN1,KN2,KN3, J0)                          \
  {                                                                            \
    const int jj = (J0);                                                       \
    const short8 v0 = *(const short8*)&Vb[(size_t)( 0 + frow) * S_LEN + jj + fk]; \
    const short8 v1 = *(const short8*)&Vb[(size_t)(16 + frow) * S_LEN + jj + fk]; \
    const short8 v2 = *(const short8*)&Vb[(size_t)(32 + frow) * S_LEN + jj + fk]; \
    const short8 v3 = *(const short8*)&Vb[(size_t)(48 + frow) * S_LEN + jj + fk]; \
    const floatx4 z = {};                                                      \
    floatx4 s00 = __builtin_amdgcn_mfma_f32_16x16x32_bf16(q00, KC0, z, 0, 0, 0); \
    s00 = __builtin_amdgcn_mfma_f32_16x16x32_bf16(q01, KC1, s00, 0, 0, 0);     \
    floatx4 s01 = __builtin_amdgcn_mfma_f32_16x16x32_bf16(q00, KC2, z, 0, 0, 0); \
    s01 = __builtin_amdgcn_mfma_f32_16x16x32_bf16(q01, KC3, s01, 0, 0, 0);     \
    floatx4 s10 = __builtin_amdgcn_mfma_f32_16x16x32_bf16(q10, KC0, z, 0, 0, 0); \
    s10 = __builtin_amdgcn_mfma_f32_16x16x32_bf16(q11, KC1, s10, 0, 0, 0);     \
    floatx4 s11 = __builtin_amdgcn_mfma_f32_16x16x32_bf16(q10, KC2, z, 0, 0, 0); \
    s11 = __builtin_amdgcn_mfma_f32_16x16x32_bf16(q11, KC3, s11, 0, 0, 0);     \
    if (jj + 32 < kend) {                                                      \
      KN0 = *(const short8*)&Kb[(size_t)(jj + 32 + frow) * HD + fk];           \
      KN1 = *(const short8*)&Kb[(size_t)(jj + 32 + frow) * HD + 32 + fk];      \
      KN2 = *(const short8*)&Kb[(size_t)(jj + 48 + frow) * HD + fk];           \
      KN3 = *(const short8*)&Kb[(size_t)(jj + 48 + frow) * HD + 32 + fk];      \
    }                                                                          \
    _Pragma("unroll")                                                          \
    for (int r = 0; r < 4; ++r) {                                              \
      const int lr   = quad * 4 + r;                                           \
      const int row0 = qm + lr;                                                \
      const int row1 = row0 + 16;                                              \
      const float p00 = (jj + frow      <= row0) ? __expf(s00[r] * 0.125f - SMAX) : 0.0f; \
      const float p01 = (jj + 16 + frow <= row0) ? __expf(s01[r] * 0.125f - SMAX) : 0.0f; \
      const float p10 = (jj + frow      <= row1) ? __expf(s10[r] * 0.125f - SMAX) : 0.0f; \
      const float p11 = (jj + 16 + frow <= row1) ? __expf(s11[r] * 0.125f - SMAX) : 0.0f; \
      lp0[r] += p00 + p01;                                                     \
      lp1[r] += p10 + p11;                                                     \
      const int sw  = (lr & 7);                                                \
      pb[lr * 64 + ((((frow) >> 3) ^ sw) << 3) + (frow & 7)]            = f2bf(p00); \
      pb[lr * 64 + ((((16 + frow) >> 3) ^ sw) << 3) + (frow & 7)]       = f2bf(p01); \
      pb[1024 + lr * 64 + ((((frow) >> 3) ^ sw) << 3) + (frow & 7)]      = f2bf(p10); \
      pb[1024 + lr * 64 + ((((16 + frow) >> 3) ^ sw) << 3) + (frow & 7)] = f2bf(p11); \
    }                                                                          \
    __builtin_amdgcn_wave_barrier();                                           \
    asm volatile("s_waitcnt lgkmcnt(0)" ::: "memory");                         \
    const short8 pf0 = *(const short8*)&pb[frow * 64 + ((quad ^ (frow & 7)) << 3)]; \
    const short8 pf1 = *(const short8*)&pb[1024 + frow * 64 + ((quad ^ (frow & 7)) << 3)]; \
    o00 = __builtin_amdgcn_mfma_f32_16x16x32_bf16(pf0, v0, o00, 0, 0, 0);      \
    o01 = __builtin_amdgcn_mfma_f32_16x16x32_bf16(pf0, v1, o01, 0, 0, 0);      \
    o02 = __builtin_amdgcn_mfma_f32_16x16x32_bf16(pf0, v2, o02, 0, 0, 0);      \
    o03 = __builtin_amdgcn_mfma_f32_16x16x32_bf16(pf0, v3, o03, 0, 0, 0);      \
    o10 = __builtin_amdgcn_mfma_f32_16x16x32_bf16(pf1, v0, o10, 0, 0, 0);      \
    o11 = __builtin_amdgcn_mfma_f32_16x16x32_bf16(pf1, v1, o11, 0, 0, 0);      \
    o12 = __builtin_amdgcn_mfma_f32_16x16x32_bf16(pf1, v2, o12, 0, 0, 0);      \
    o13 = __builtin_amdgcn_mfma_f32_16x16x32_bf16(pf1, v3, o13, 0, 0, 0);      \
    __builtin_amdgcn_wave_barrier();                                           \
  }

__global__ __launch_bounds__(256)
void flash_attn(const ushort* __restrict__ Q, const ushort* __restrict__ Kk,
                const ushort* __restrict__ Vt, ushort* __restrict__ O) {
  __shared__ ushort pbuf[4 * 2048];
  const int wave = threadIdx.x >> 6, lane = threadIdx.x & 63;
  const int bb  = blockIdx.x;
  const int vid = (bb & 7) * 128 + (bb >> 3);   // bijective XCD remap (1024 % 8 == 0)
  const int u   = vid >> 4;                     // (b,h); 8 consecutive heads per XCD
  const int g   = vid & 15;
  const int rot = (vid >> 5) & 3;
  const int m   = (wave + rot) & 3;             // rotate qt class across SIMDs
  const int qt  = (m == 0) ? g : (m == 1) ? 31 - g : (m == 2) ? 32 + g : 63 - g;
  const int h = u & 31, b = u >> 5;
  const int qm = qt * 32;
  const int frow = lane & 15, quad = lane >> 4, fk = quad * 8;

  const ushort* Qb = Q  + (((size_t)b * NH  + h)       * S_LEN + qm) * HD;
  const ushort* Kb = Kk + ((size_t)b * NKV + (h >> 2)) * S_LEN * HD;
  const ushort* Vb = Vt + ((size_t)b * NKV + (h >> 2)) * HD * S_LEN;
  ushort* pb = pbuf + wave * 2048;

  const short8 q00 = *(const short8*)&Qb[frow * HD + fk];
  const short8 q01 = *(const short8*)&Qb[frow * HD + 32 + fk];
  const short8 q10 = *(const short8*)&Qb[(16 + frow) * HD + fk];
  const short8 q11 = *(const short8*)&Qb[(16 + frow) * HD + 32 + fk];

  floatx4 o00 = {}, o01 = {}, o02 = {}, o03 = {};
  floatx4 o10 = {}, o11 = {}, o12 = {}, o13 = {};
  float lp0[4] = {0.f, 0.f, 0.f, 0.f};
  float lp1[4] = {0.f, 0.f, 0.f, 0.f};
  const int kend = qm + 32;

  short8 kA0, kA1, kA2, kA3, kB0, kB1, kB2, kB3;
  kA0 = *(const short8*)&Kb[(size_t)(frow) * HD + fk];
  kA1 = *(const short8*)&Kb[(size_t)(frow) * HD + 32 + fk];
  kA2 = *(const short8*)&Kb[(size_t)(16 + frow) * HD + fk];
  kA3 = *(const short8*)&Kb[(size_t)(16 + frow) * HD + 32 + fk];

  for (int j0 = 0; j0 < kend; j0 += 64) {
    FA_BODY(kA0, kA1, kA2, kA3, kB0, kB1, kB2, kB3, j0);
    if (j0 + 32 < kend) {
      FA_BODY(kB0, kB1, kB2, kB3, kA0, kA1, kA2, kA3, j0 + 32);
    }
  }

  // one-shot denominator reduce across the 16 cols (frow) of each row
#pragma unroll
  for (int r = 0; r < 4; ++r) {
#pragma unroll
    for (int d = 1; d < 16; d <<= 1) {
      lp0[r] += __shfl_xor(lp0[r], d);
      lp1[r] += __shfl_xor(lp1[r], d);
    }
  }

  const size_t obase = ((size_t)b * S_LEN + qm) * HID + (size_t)h * HD;
#pragma unroll
  for (int r = 0; r < 4; ++r) {
    const float i0 = 1.0f / lp0[r];
    const float i1 = 1.0f / lp1[r];
    const size_t r0 = obase + (size_t)(quad * 4 + r) * HID;
    const size_t r1 = obase + (size_t)(16 + quad * 4 + r) * HID;
    O[r0 +  0 + frow] = f2bf(o00[r] * i0);
    O[r0 + 16 + frow] = f2bf(o01[r] * i0);
    O[r0 + 32 + frow] = f2bf(o02[r] * i0);
    O[r0 + 48 + frow] = f2bf(o03[r] * i0);
    O[r1 +  0 + frow] = f2bf(o10[r] * i1);
    O[r1 + 16 + frow] = f2bf(o11[r] * i1);
    O[r1 + 32 + frow] = f2bf(o12[r] * i1);
    O[r1 + 48 + frow] = f2bf(o13[r] * i1);
  }
}

// ---------------------------------------------------------------------------
// Workspace layout — 60 MiB:
//   R0 @ 0        (16 MiB): hb (hidden bf16) -> Q  (after gemm1)
//   R1 @ 16 MiB   (12 MiB): wq (w_qkv bf16)  -> wo (after gemm1)
//   R2 @ 28 MiB   (24 MiB): qkv              -> O  (after ln_rope)
//   R3 @ 52 MiB   ( 4 MiB): K
//   R4 @ 56 MiB   ( 4 MiB): Vt
// Output: fp32, written directly by gemm_nt<false>.
// ---------------------------------------------------------------------------
extern "C" void kernel_launch(void* const* d_in, const int* in_sizes, int n_in,
                              void* d_out, int out_size, void* d_ws, size_t ws_size,
                              hipStream_t stream) {
  (void)in_sizes; (void)n_in; (void)out_size; (void)ws_size;
  const int*   pos    = (const int*)d_in[0];
  const float* hidden = (const float*)d_in[1];
  const float* w_qkv  = (const float*)d_in[2];
  const float* q_ln_w = (const float*)d_in[3];
  const float* k_ln_w = (const float*)d_in[4];
  const float* w_o    = (const float*)d_in[5];

  char* ws = (char*)d_ws;
  ushort* hb  = (ushort*)(ws);
  ushort* Q   = (ushort*)(ws);                   // reuse R0
  ushort* wq  = (ushort*)(ws + 16777216);
  ushort* wo  = (ushort*)(ws + 16777216);        // reuse R1
  ushort* qkv = (ushort*)(ws + 29360128);
  ushort* O   = (ushort*)(ws + 29360128);        // reuse R2
  ushort* Kk  = (ushort*)(ws + 54525952);
  ushort* Vt  = (ushort*)(ws + 58720256);

  cvt_f32_bf16<<<dim3(4096), 256, 0, stream>>>(hidden, hb, 8388608 / 8);
  cvt_f32_bf16<<<dim3(3072), 256, 0, stream>>>(w_qkv, wq, 6291456 / 8);
  gemm_nt<true><<<dim3(QKV_N / 128, ROWS / 128), 256, 0, stream>>>(
      hb, wq, qkv, ROWS, QKV_N, HID);
  ln_rope_split<<<dim3(ROWS * 48 / 4), 256, 0, stream>>>(
      qkv, pos, q_ln_w, k_ln_w, Q, Kk, Vt);
  cvt_f32_bf16<<<dim3(2048), 256, 0, stream>>>(w_o, wo, 4194304 / 8);
  flash_attn<<<dim3(1024), 256, 0, stream>>>(Q, Kk, Vt, O);
  gemm_nt<false><<<dim3(HID / 128, ROWS / 128), 256, 0, stream>>>(
      O, wo, d_out, ROWS, HID, HID);
}

// Round 2
// 426.195 us; speedup vs baseline: 1.2933x; 1.0306x over previous
//
#include <hip/hip_runtime.h>
#include <hip/hip_bf16.h>

#define S_LEN 2048
#define HID   2048
#define NH    32
#define NKV   8
#define HD    64
#define ROT   16
#define QKV_N 3072
#define ROWS  4096   // B*S

typedef __attribute__((ext_vector_type(8))) short short8;
typedef __attribute__((ext_vector_type(8))) unsigned short ushort8;
typedef __attribute__((ext_vector_type(4))) float floatx4;

static __device__ __forceinline__ float bf2f(ushort u) {
  union { unsigned int i; float f; } v; v.i = ((unsigned int)u) << 16; return v.f;
}
static __device__ __forceinline__ ushort f2bf(float f) {
  union { __hip_bfloat16 h; ushort u; } v; v.h = __float2bfloat16(f); return v.u;
}

// ---------------------------------------------------------------------------
// fp32 -> bf16 convert, 8 elems/thread (inputs are fp32)
// ---------------------------------------------------------------------------
__global__ __launch_bounds__(256)
void cvt_f32_bf16(const float* __restrict__ in, ushort* __restrict__ out, int n8) {
  const int i = blockIdx.x * 256 + threadIdx.x;
  if (i >= n8) return;
  const float4 a = ((const float4*)in)[2 * i];
  const float4 b = ((const float4*)in)[2 * i + 1];
  ushort8 o;
  o[0] = f2bf(a.x); o[1] = f2bf(a.y); o[2] = f2bf(a.z); o[3] = f2bf(a.w);
  o[4] = f2bf(b.x); o[5] = f2bf(b.y); o[6] = f2bf(b.z); o[7] = f2bf(b.w);
  ((ushort8*)out)[i] = o;
}

// ---------------------------------------------------------------------------
// NT GEMM (m97 structure): 128x128 tile, BK=32, global_load_lds width-16,
// 4 waves x 4x4 mfma_f32_16x16x32_bf16. OUT_BF16 ? bf16 C : fp32 C.
// ---------------------------------------------------------------------------
template<bool OUT_BF16>
__global__ __launch_bounds__(256, 2)
void gemm_nt(const ushort* __restrict__ A, const ushort* __restrict__ B,
             void* __restrict__ Cout, int M, int N, int K) {
  __shared__ ushort lA[128 * 32];
  __shared__ ushort lB[128 * 32];
  const int tid  = threadIdx.x;
  const int wave = tid >> 6, lane = tid & 63;
  const int wr = (wave >> 1) * 64, wc = (wave & 1) * 64;
  const int frow = lane & 15, quad = lane >> 4;
  const int fk = quad * 8;
  const int srow = lane >> 2, skk = (lane & 3) * 8;
  const size_t bm = (size_t)blockIdx.y * 128;
  const size_t bn = (size_t)blockIdx.x * 128;
  const ushort* Ab = A + bm * K;
  const ushort* Bb = B + bn * K;
  floatx4 acc[4][4] = {};

  for (int k0 = 0; k0 < K; k0 += 32) {
    __syncthreads();
    {
      const int c0 = wave * 2;
      const ushort* ga = Ab + (size_t)(c0 * 16 + srow) * K + (k0 + skk);
      const ushort* gb = Bb + (size_t)(c0 * 16 + srow) * K + (k0 + skk);
      __builtin_amdgcn_global_load_lds((const __attribute__((address_space(1))) void*)ga,
          (__attribute__((address_space(3))) void*)&lA[c0 * 512], 16, 0, 0);
      __builtin_amdgcn_global_load_lds((const __attribute__((address_space(1))) void*)gb,
          (__attribute__((address_space(3))) void*)&lB[c0 * 512], 16, 0, 0);
      __builtin_amdgcn_global_load_lds((const __attribute__((address_space(1))) void*)(ga + (size_t)16 * K),
          (__attribute__((address_space(3))) void*)&lA[(c0 + 1) * 512], 16, 0, 0);
      __builtin_amdgcn_global_load_lds((const __attribute__((address_space(1))) void*)(gb + (size_t)16 * K),
          (__attribute__((address_space(3))) void*)&lB[(c0 + 1) * 512], 16, 0, 0);
    }
    __syncthreads();

    short8 af[4], bfr[4];
#pragma unroll
    for (int i = 0; i < 4; ++i)
      af[i] = *(const short8*)&lA[(wr + i * 16 + frow) * 32 + fk];
#pragma unroll
    for (int i = 0; i < 4; ++i)
      bfr[i] = *(const short8*)&lB[(wc + i * 16 + frow) * 32 + fk];
#pragma unroll
    for (int i = 0; i < 4; ++i)
#pragma unroll
      for (int j = 0; j < 4; ++j)
        acc[i][j] = __builtin_amdgcn_mfma_f32_16x16x32_bf16(af[i], bfr[j], acc[i][j], 0, 0, 0);
  }

  const int r0 = quad * 4;
#pragma unroll
  for (int i = 0; i < 4; ++i) {
#pragma unroll
    for (int r = 0; r < 4; ++r) {
      const size_t row = bm + wr + i * 16 + r0 + r;
#pragma unroll
      for (int j = 0; j < 4; ++j) {
        const size_t col = bn + wc + j * 16 + frow;
        if (OUT_BF16) ((ushort*)Cout)[row * N + col] = f2bf(acc[i][j][r]);
        else          ((float*)Cout)[row * N + col] = acc[i][j][r];
      }
    }
  }
}

// ---------------------------------------------------------------------------
// Per-head LayerNorm + partial NeoX RoPE + split. One wave per (row, slot).
// slot 0..31 = q, 32..39 = k, 40..47 = v. LN weights fp32.
// Q -> (b,h,s,d); K -> (b,kv,s,d); V -> (b,kv,d,s) transposed for flash.
// ---------------------------------------------------------------------------
__global__ __launch_bounds__(256)
void ln_rope_split(const ushort* __restrict__ qkv, const int* __restrict__ pos_ids,
                   const float* __restrict__ qw, const float* __restrict__ kw,
                   ushort* __restrict__ Q, ushort* __restrict__ Kk, ushort* __restrict__ Vt) {
  const int gw   = (blockIdx.x * 256 + threadIdx.x) >> 6;
  const int lane = threadIdx.x & 63;
  const int row  = gw / 48;
  const int slot = gw - row * 48;
  const int b = row >> 11, s = row & 2047;
  const float x = bf2f(qkv[(size_t)row * QKV_N + slot * 64 + lane]);

  if (slot < 40) {
    float s1 = x, s2 = x * x;
#pragma unroll
    for (int d = 1; d < 64; d <<= 1) { s1 += __shfl_xor(s1, d); s2 += __shfl_xor(s2, d); }
    const float mu  = s1 * (1.0f / 64.0f);
    const float var = s2 * (1.0f / 64.0f) - mu * mu;
    const float w = (slot < 32) ? qw[slot * 64 + lane] : kw[(slot - 32) * 64 + lane];
    float y = (x - mu) * rsqrtf(var + 1e-5f) * w;
    if (lane < ROT) {
      const int dd = lane & 7;
      const float invf = powf(10000.0f, -(float)dd * 0.125f);
      const float fr = (float)pos_ids[row] * invf;
      const float c = cosf(fr), sn = sinf(fr);
      const float yp = __shfl_xor(y, 8);
      y = (lane < 8) ? (y * c - yp * sn) : (y * c + yp * sn);
    }
    if (slot < 32)
      Q[(((size_t)b * NH + slot) * S_LEN + s) * HD + lane] = f2bf(y);
    else
      Kk[(((size_t)b * NKV + (slot - 32)) * S_LEN + s) * HD + lane] = f2bf(y);
  } else {
    const int kvh = slot - 40;
    Vt[(((size_t)b * NKV + kvh) * HD + lane) * S_LEN + s] = f2bf(x);
  }
}

// ---------------------------------------------------------------------------
// Causal GQA flash attention, FIXED-CAP softmax (no online rescaling):
// LayerNorm bounds |q|,|k| <= 8 -> s = q.k/8 in [-8.1,8.1]; p = exp(s - 9)
// cannot overflow; softmax shift-invariance makes it exact.
//
// v3 structure (occupancy/balance fix — v2 occupancy was 14%, straggler
// waves ran alone):
//  * Split-K across a 2-wave block: block owns one (b,h,qt) strip; wave0
//    takes KV tiles [0,Th), wave1 [Th,T). Fixed-cap softmax partials are
//    additively combinable (no max tracking): un-normalized o + lp summed
//    once per block via LDS (stride-33 pad, conflict-free). Max per-wave
//    work 64 -> 32 tiles.
//  * LPT grid: 4096 one-strip blocks, qt descending in dispatch order;
//    per-CU work 520 tiles over 12 resident wave slots (launch_bounds 128,3)
//    -> no straggler floor.
//  * XCD locality: xcd = bb&7 owns 8 consecutive heads (2 KV heads, ~2MB
//    K+V L2-resident); qt descends within each XCD.
//  * Retains v2: QBLK=32, K reg double-buffer, V issue-early/use-late,
//    XOR-swizzled P bounce buffer.
// ---------------------------------------------------------------------------
#define SMAX 9.0f

#define FA_BODY(KC0,KC1,KC2,KC3, KN0,KN1,KN2,KN3, TI)                          \
  {                                                                            \
    const int jj = (TI) * 32;                                                  \
    const short8 v0 = *(const short8*)&Vb[(size_t)( 0 + frow) * S_LEN + jj + fk]; \
    const short8 v1 = *(const short8*)&Vb[(size_t)(16 + frow) * S_LEN + jj + fk]; \
    const short8 v2 = *(const short8*)&Vb[(size_t)(32 + frow) * S_LEN + jj + fk]; \
    const short8 v3 = *(const short8*)&Vb[(size_t)(48 + frow) * S_LEN + jj + fk]; \
    const floatx4 z = {};                                                      \
    floatx4 s00 = __builtin_amdgcn_mfma_f32_16x16x32_bf16(q00, KC0, z, 0, 0, 0); \
    s00 = __builtin_amdgcn_mfma_f32_16x16x32_bf16(q01, KC1, s00, 0, 0, 0);     \
    floatx4 s01 = __builtin_amdgcn_mfma_f32_16x16x32_bf16(q00, KC2, z, 0, 0, 0); \
    s01 = __builtin_amdgcn_mfma_f32_16x16x32_bf16(q01, KC3, s01, 0, 0, 0);     \
    floatx4 s10 = __builtin_amdgcn_mfma_f32_16x16x32_bf16(q10, KC0, z, 0, 0, 0); \
    s10 = __builtin_amdgcn_mfma_f32_16x16x32_bf16(q11, KC1, s10, 0, 0, 0);     \
    floatx4 s11 = __builtin_amdgcn_mfma_f32_16x16x32_bf16(q10, KC2, z, 0, 0, 0); \
    s11 = __builtin_amdgcn_mfma_f32_16x16x32_bf16(q11, KC3, s11, 0, 0, 0);     \
    if ((TI) + 1 < tb) {                                                       \
      const int jn = ((TI) + 1) * 32;                                          \
      KN0 = *(const short8*)&Kb[(size_t)(jn + frow) * HD + fk];                \
      KN1 = *(const short8*)&Kb[(size_t)(jn + frow) * HD + 32 + fk];           \
      KN2 = *(const short8*)&Kb[(size_t)(jn + 16 + frow) * HD + fk];           \
      KN3 = *(const short8*)&Kb[(size_t)(jn + 16 + frow) * HD + 32 + fk];      \
    }                                                                          \
    _Pragma("unroll")                                                          \
    for (int r = 0; r < 4; ++r) {                                              \
      const int lr   = quad * 4 + r;                                           \
      const int row0 = qm + lr;                                                \
      const int row1 = row0 + 16;                                              \
      const float p00 = (jj + frow      <= row0) ? __expf(s00[r] * 0.125f - SMAX) : 0.0f; \
      const float p01 = (jj + 16 + frow <= row0) ? __expf(s01[r] * 0.125f - SMAX) : 0.0f; \
      const float p10 = (jj + frow      <= row1) ? __expf(s10[r] * 0.125f - SMAX) : 0.0f; \
      const float p11 = (jj + 16 + frow <= row1) ? __expf(s11[r] * 0.125f - SMAX) : 0.0f; \
      lp0[r] += p00 + p01;                                                     \
      lp1[r] += p10 + p11;                                                     \
      const int sw  = (lr & 7);                                                \
      pb[lr * 64 + ((((frow) >> 3) ^ sw) << 3) + (frow & 7)]             = f2bf(p00); \
      pb[lr * 64 + ((((16 + frow) >> 3) ^ sw) << 3) + (frow & 7)]        = f2bf(p01); \
      pb[1024 + lr * 64 + ((((frow) >> 3) ^ sw) << 3) + (frow & 7)]      = f2bf(p10); \
      pb[1024 + lr * 64 + ((((16 + frow) >> 3) ^ sw) << 3) + (frow & 7)] = f2bf(p11); \
    }                                                                          \
    __builtin_amdgcn_wave_barrier();                                           \
    asm volatile("s_waitcnt lgkmcnt(0)" ::: "memory");                         \
    const short8 pf0 = *(const short8*)&pb[frow * 64 + ((quad ^ (frow & 7)) << 3)]; \
    const short8 pf1 = *(const short8*)&pb[1024 + frow * 64 + ((quad ^ (frow & 7)) << 3)]; \
    o00 = __builtin_amdgcn_mfma_f32_16x16x32_bf16(pf0, v0, o00, 0, 0, 0);      \
    o01 = __builtin_amdgcn_mfma_f32_16x16x32_bf16(pf0, v1, o01, 0, 0, 0);      \
    o02 = __builtin_amdgcn_mfma_f32_16x16x32_bf16(pf0, v2, o02, 0, 0, 0);      \
    o03 = __builtin_amdgcn_mfma_f32_16x16x32_bf16(pf0, v3, o03, 0, 0, 0);      \
    o10 = __builtin_amdgcn_mfma_f32_16x16x32_bf16(pf1, v0, o10, 0, 0, 0);      \
    o11 = __builtin_amdgcn_mfma_f32_16x16x32_bf16(pf1, v1, o11, 0, 0, 0);      \
    o12 = __builtin_amdgcn_mfma_f32_16x16x32_bf16(pf1, v2, o12, 0, 0, 0);      \
    o13 = __builtin_amdgcn_mfma_f32_16x16x32_bf16(pf1, v3, o13, 0, 0, 0);      \
    __builtin_amdgcn_wave_barrier();                                           \
  }

__global__ __launch_bounds__(128, 3)
void flash_attn(const ushort* __restrict__ Q, const ushort* __restrict__ Kk,
                const ushort* __restrict__ Vt, ushort* __restrict__ O) {
  __shared__ ushort pbuf[2 * 2048];
  __shared__ float  obuf[64 * 33];
  __shared__ float  lpbuf[64 * 8];
  const int wave = threadIdx.x >> 6, lane = threadIdx.x & 63;
  const int bb  = blockIdx.x;
  const int xcd = bb & 7;
  const int j   = bb >> 3;                 // 0..511 per XCD
  const int qt  = 63 - (j >> 3);           // LPT: heavy strips dispatch first
  const int bh  = xcd * 8 + (j & 7);       // 8 consecutive heads per XCD
  const int h = bh & 31, b = bh >> 5;
  const int qm = qt * 32;
  const int frow = lane & 15, quad = lane >> 4, fk = quad * 8;

  const ushort* Qb = Q  + (((size_t)b * NH  + h)       * S_LEN + qm) * HD;
  const ushort* Kb = Kk + ((size_t)b * NKV + (h >> 2)) * S_LEN * HD;
  const ushort* Vb = Vt + ((size_t)b * NKV + (h >> 2)) * HD * S_LEN;
  ushort* pb = pbuf + wave * 2048;

  const short8 q00 = *(const short8*)&Qb[frow * HD + fk];
  const short8 q01 = *(const short8*)&Qb[frow * HD + 32 + fk];
  const short8 q10 = *(const short8*)&Qb[(16 + frow) * HD + fk];
  const short8 q11 = *(const short8*)&Qb[(16 + frow) * HD + 32 + fk];

  floatx4 o00 = {}, o01 = {}, o02 = {}, o03 = {};
  floatx4 o10 = {}, o11 = {}, o12 = {}, o13 = {};
  float lp0[4] = {0.f, 0.f, 0.f, 0.f};
  float lp1[4] = {0.f, 0.f, 0.f, 0.f};

  // split-K: tiles [0,Th) -> wave0, [Th,T) -> wave1
  const int T  = qt + 1;
  const int Th = (T + 1) >> 1;
  const int ta = wave ? Th : 0;
  const int tb = wave ? T : Th;

  short8 kA0, kA1, kA2, kA3, kB0, kB1, kB2, kB3;
  if (ta < tb) {
    const int j0 = ta * 32;
    kA0 = *(const short8*)&Kb[(size_t)(j0 + frow) * HD + fk];
    kA1 = *(const short8*)&Kb[(size_t)(j0 + frow) * HD + 32 + fk];
    kA2 = *(const short8*)&Kb[(size_t)(j0 + 16 + frow) * HD + fk];
    kA3 = *(const short8*)&Kb[(size_t)(j0 + 16 + frow) * HD + 32 + fk];
  }

  int t = ta;
  for (; t + 1 < tb; t += 2) {
    FA_BODY(kA0, kA1, kA2, kA3, kB0, kB1, kB2, kB3, t);
    FA_BODY(kB0, kB1, kB2, kB3, kA0, kA1, kA2, kA3, t + 1);
  }
  if (t < tb) {
    FA_BODY(kA0, kA1, kA2, kA3, kB0, kB1, kB2, kB3, t);
  }

  // per-wave denominator reduce across the 16 cols (frow) of each row
#pragma unroll
  for (int r = 0; r < 4; ++r) {
#pragma unroll
    for (int d = 1; d < 16; d <<= 1) {
      lp0[r] += __shfl_xor(lp0[r], d);
      lp1[r] += __shfl_xor(lp1[r], d);
    }
  }

  // combine wave1's partials into wave0 (stride-33 pad -> conflict-free)
  if (wave == 1) {
#pragma unroll
    for (int r = 0; r < 4; ++r) {
      obuf[lane * 33 +  0 + r] = o00[r];
      obuf[lane * 33 +  4 + r] = o01[r];
      obuf[lane * 33 +  8 + r] = o02[r];
      obuf[lane * 33 + 12 + r] = o03[r];
      obuf[lane * 33 + 16 + r] = o10[r];
      obuf[lane * 33 + 20 + r] = o11[r];
      obuf[lane * 33 + 24 + r] = o12[r];
      obuf[lane * 33 + 28 + r] = o13[r];
      lpbuf[lane * 8 + r]     = lp0[r];
      lpbuf[lane * 8 + 4 + r] = lp1[r];
    }
  }
  __syncthreads();
  if (wave != 0) return;

#pragma unroll
  for (int r = 0; r < 4; ++r) {
    o00[r] += obuf[lane * 33 +  0 + r];
    o01[r] += obuf[lane * 33 +  4 + r];
    o02[r] += obuf[lane * 33 +  8 + r];
    o03[r] += obuf[lane * 33 + 12 + r];
    o10[r] += obuf[lane * 33 + 16 + r];
    o11[r] += obuf[lane * 33 + 20 + r];
    o12[r] += obuf[lane * 33 + 24 + r];
    o13[r] += obuf[lane * 33 + 28 + r];
    lp0[r] += lpbuf[lane * 8 + r];
    lp1[r] += lpbuf[lane * 8 + 4 + r];
  }

  const size_t obase = ((size_t)b * S_LEN + qm) * HID + (size_t)h * HD;
#pragma unroll
  for (int r = 0; r < 4; ++r) {
    const float i0 = 1.0f / lp0[r];
    const float i1 = 1.0f / lp1[r];
    const size_t r0 = obase + (size_t)(quad * 4 + r) * HID;
    const size_t r1 = obase + (size_t)(16 + quad * 4 + r) * HID;
    O[r0 +  0 + frow] = f2bf(o00[r] * i0);
    O[r0 + 16 + frow] = f2bf(o01[r] * i0);
    O[r0 + 32 + frow] = f2bf(o02[r] * i0);
    O[r0 + 48 + frow] = f2bf(o03[r] * i0);
    O[r1 +  0 + frow] = f2bf(o10[r] * i1);
    O[r1 + 16 + frow] = f2bf(o11[r] * i1);
    O[r1 + 32 + frow] = f2bf(o12[r] * i1);
    O[r1 + 48 + frow] = f2bf(o13[r] * i1);
  }
}

// ---------------------------------------------------------------------------
// Workspace layout — 60 MiB:
//   R0 @ 0        (16 MiB): hb (hidden bf16) -> Q  (after gemm1)
//   R1 @ 16 MiB   (12 MiB): wq (w_qkv bf16)  -> wo (after gemm1)
//   R2 @ 28 MiB   (24 MiB): qkv              -> O  (after ln_rope)
//   R3 @ 52 MiB   ( 4 MiB): K
//   R4 @ 56 MiB   ( 4 MiB): Vt
// Output: fp32, written directly by gemm_nt<false>.
// ---------------------------------------------------------------------------
extern "C" void kernel_launch(void* const* d_in, const int* in_sizes, int n_in,
                              void* d_out, int out_size, void* d_ws, size_t ws_size,
                              hipStream_t stream) {
  (void)in_sizes; (void)n_in; (void)out_size; (void)ws_size;
  const int*   pos    = (const int*)d_in[0];
  const float* hidden = (const float*)d_in[1];
  const float* w_qkv  = (const float*)d_in[2];
  const float* q_ln_w = (const float*)d_in[3];
  const float* k_ln_w = (const float*)d_in[4];
  const float* w_o    = (const float*)d_in[5];

  char* ws = (char*)d_ws;
  ushort* hb  = (ushort*)(ws);
  ushort* Q   = (ushort*)(ws);                   // reuse R0
  ushort* wq  = (ushort*)(ws + 16777216);
  ushort* wo  = (ushort*)(ws + 16777216);        // reuse R1
  ushort* qkv = (ushort*)(ws + 29360128);
  ushort* O   = (ushort*)(ws + 29360128);        // reuse R2
  ushort* Kk  = (ushort*)(ws + 54525952);
  ushort* Vt  = (ushort*)(ws + 58720256);

  cvt_f32_bf16<<<dim3(4096), 256, 0, stream>>>(hidden, hb, 8388608 / 8);
  cvt_f32_bf16<<<dim3(3072), 256, 0, stream>>>(w_qkv, wq, 6291456 / 8);
  gemm_nt<true><<<dim3(QKV_N / 128, ROWS / 128), 256, 0, stream>>>(
      hb, wq, qkv, ROWS, QKV_N, HID);
  ln_rope_split<<<dim3(ROWS * 48 / 4), 256, 0, stream>>>(
      qkv, pos, q_ln_w, k_ln_w, Q, Kk, Vt);
  cvt_f32_bf16<<<dim3(2048), 256, 0, stream>>>(w_o, wo, 4194304 / 8);
  flash_attn<<<dim3(4096), 128, 0, stream>>>(Q, Kk, Vt, O);
  gemm_nt<false><<<dim3(HID / 128, ROWS / 128), 256, 0, stream>>>(
      O, wo, d_out, ROWS, HID, HID);
}